// Round 1
// baseline (521.567 us; speedup 1.0000x reference)
//
#include <hip/hip_runtime.h>

#define NEG 1000000000000.0f

typedef __attribute__((ext_vector_type(4))) float f32x4;
typedef __attribute__((ext_vector_type(8))) short bf16x8;

__device__ __forceinline__ unsigned short f2bf(float f) {
    union { float f; unsigned u; } a;
    a.f = f;
    unsigned u = a.u;
    return (unsigned short)((u + 0x7FFFu + ((u >> 16) & 1u)) >> 16);
}

// ---------------- kernel 0a: fp32 -> bf16 convert (hidden_states) ----------
__global__ void cvt_bf16_kernel(const float* __restrict__ in,
                                unsigned short* __restrict__ out, int n4) {
    int i = blockIdx.x * blockDim.x + threadIdx.x;
    if (i < n4) {
        float4 v = ((const float4*)in)[i];
        ushort4 o;
        o.x = f2bf(v.x); o.y = f2bf(v.y); o.z = f2bf(v.z); o.w = f2bf(v.w);
        ((ushort4*)out)[i] = o;
    }
}

// ---------------- kernel 0b: W [768][1536] fp32 -> Wt [1536][768] bf16 -----
__global__ void transpose_w_kernel(const float* __restrict__ W,
                                   unsigned short* __restrict__ Wt) {
    __shared__ float tile[32][33];
    int n0 = blockIdx.x * 32, k0 = blockIdx.y * 32;
    int tx = threadIdx.x & 31, ty = threadIdx.x >> 5;   // ty: 0..7
    #pragma unroll
    for (int r = 0; r < 32; r += 8)
        tile[ty + r][tx] = W[(k0 + ty + r) * 1536 + n0 + tx];   // tile[k_l][n_l]
    __syncthreads();
    #pragma unroll
    for (int r = 0; r < 32; r += 8)
        Wt[(n0 + ty + r) * 768 + k0 + tx] = f2bf(tile[tx][ty + r]);
}

// ---------------- kernel 0c: RoPE sin/cos tables [1024][32] ----------------
__global__ void rope_table_kernel(float* __restrict__ cosT, float* __restrict__ sinT) {
    int idx = blockIdx.x * blockDim.x + threadIdx.x;   // t*32 + i
    int t = idx >> 5, i = idx & 31;
    float inv = powf(10000.0f, -(float)i / 32.0f);     // 10000^(-2i/64)
    float ang = (float)t * inv;
    cosT[idx] = cosf(ang);
    sinT[idx] = sinf(ang);
}

// ---------------- kernel 1: proj GEMM + bias + RoPE -> q,k bf16 ------------
// A = hs_bf16 [8192][768], Bt = Wt_bf16 [1536][768]; C tile 128x128, BK=64.
__global__ __launch_bounds__(256) void proj_rope_kernel(
    const unsigned short* __restrict__ A,
    const unsigned short* __restrict__ Bt,
    const float* __restrict__ bias,
    const float* __restrict__ cosT, const float* __restrict__ sinT,
    unsigned short* __restrict__ qout, unsigned short* __restrict__ kout)
{
    __shared__ unsigned short As[128][72];   // +8 pad: 2-way bank alias (free)
    __shared__ unsigned short Bs[128][72];
    const int tid = threadIdx.x;
    const int lane = tid & 63, wid = tid >> 6;
    const int wm = wid >> 1, wn = wid & 1;
    const int bm = blockIdx.y * 128, bn = blockIdx.x * 128;
    const int sr = tid >> 3, sc = (tid & 7) * 8;
    const int l15 = lane & 15, l4 = lane >> 4;

    f32x4 acc[4][4] = {};

    for (int k0 = 0; k0 < 768; k0 += 64) {
        __syncthreads();
        #pragma unroll
        for (int rr = 0; rr < 128; rr += 32) {
            *(bf16x8*)&As[sr + rr][sc] =
                *(const bf16x8*)&A[(bm + sr + rr) * 768 + k0 + sc];
            *(bf16x8*)&Bs[sr + rr][sc] =
                *(const bf16x8*)&Bt[(bn + sr + rr) * 768 + k0 + sc];
        }
        __syncthreads();
        #pragma unroll
        for (int ks = 0; ks < 2; ++ks) {
            bf16x8 af[4], bq[4];
            #pragma unroll
            for (int i = 0; i < 4; ++i) {
                af[i] = *(const bf16x8*)&As[wm * 64 + i * 16 + l15][ks * 32 + l4 * 8];
                bq[i] = *(const bf16x8*)&Bs[wn * 64 + i * 16 + l15][ks * 32 + l4 * 8];
            }
            #pragma unroll
            for (int i = 0; i < 4; ++i)
                #pragma unroll
                for (int j = 0; j < 4; ++j)
                    acc[i][j] = __builtin_amdgcn_mfma_f32_16x16x32_bf16(
                        af[i], bq[j], acc[i][j], 0, 0, 0);
        }
    }

    // epilogue: bias + RoPE (pair via shfl_xor lane^1) + scatter to q/k bf16
    const int rbase = bm + wm * 64 + l4 * 4;
    const int cbase = bn + wn * 64 + l15;
    #pragma unroll
    for (int mi = 0; mi < 4; ++mi) {
        #pragma unroll
        for (int ni = 0; ni < 4; ++ni) {
            const int n = cbase + ni * 16;
            const float bv = bias[n];
            const int h = n >> 7, w = n & 127;
            const int d = w & 63, fi = d >> 1;
            unsigned short* __restrict__ dst = (w < 64) ? qout : kout;
            #pragma unroll
            for (int j = 0; j < 4; ++j) {
                const int m = rbase + mi * 16 + j;
                const int t = m & 1023, bb = m >> 10;
                float v = acc[mi][ni][j] + bv;
                float p = __shfl_xor(v, 1, 64);
                float c = cosT[t * 32 + fi], s = sinT[t * 32 + fi];
                float r = (d & 1) ? fmaf(v, c, p * s) : fmaf(v, c, -p * s);
                dst[((bb * 12 + h) * 1024 + t) * 64 + d] = f2bf(r);
            }
        }
    }
}

// ---------------- kernel 2: logits = q@k^T, mask, causal, scale ------------
__global__ __launch_bounds__(256) void logits_kernel(
    const unsigned short* __restrict__ q, const unsigned short* __restrict__ k,
    const int* __restrict__ mask, float* __restrict__ out)
{
    __shared__ unsigned short Qs[128][72];
    __shared__ unsigned short Ks[128][72];
    const int tid = threadIdx.x;
    const int lane = tid & 63, wid = tid >> 6;
    const int wm = wid >> 1, wn = wid & 1;
    const int tn = blockIdx.x, tm = blockIdx.y, z = blockIdx.z;  // z = b*12+h
    const int bb = z / 12;
    const int sr = tid >> 3, sc = (tid & 7) * 8;
    const int l15 = lane & 15, l4 = lane >> 4;

    f32x4 acc[4][4] = {};

    const int qbase = (z * 1024 + tm * 128) * 64;
    const int kbase = (z * 1024 + tn * 128) * 64;
    #pragma unroll
    for (int rr = 0; rr < 128; rr += 32) {
        *(bf16x8*)&Qs[sr + rr][sc] = *(const bf16x8*)&q[qbase + (sr + rr) * 64 + sc];
        *(bf16x8*)&Ks[sr + rr][sc] = *(const bf16x8*)&k[kbase + (sr + rr) * 64 + sc];
    }
    __syncthreads();
    #pragma unroll
    for (int ks = 0; ks < 2; ++ks) {
        bf16x8 af[4], bq[4];
        #pragma unroll
        for (int i = 0; i < 4; ++i) {
            af[i] = *(const bf16x8*)&Qs[wm * 64 + i * 16 + l15][ks * 32 + l4 * 8];
            bq[i] = *(const bf16x8*)&Ks[wn * 64 + i * 16 + l15][ks * 32 + l4 * 8];
        }
        #pragma unroll
        for (int i = 0; i < 4; ++i)
            #pragma unroll
            for (int j = 0; j < 4; ++j)
                acc[i][j] = __builtin_amdgcn_mfma_f32_16x16x32_bf16(
                    af[i], bq[j], acc[i][j], 0, 0, 0);
    }

    const int rbase = tm * 128 + wm * 64 + l4 * 4;
    const int cbase = tn * 128 + wn * 64 + l15;
    #pragma unroll
    for (int ni = 0; ni < 4; ++ni) {
        const int n = cbase + ni * 16;
        const float mv = (float)mask[bb * 1024 + n];
        const float addc = -(1.0f - mv) * NEG;
        #pragma unroll
        for (int mi = 0; mi < 4; ++mi) {
            #pragma unroll
            for (int j = 0; j < 4; ++j) {
                const int m = rbase + mi * 16 + j;
                float s = acc[mi][ni][j];
                out[(z * 1024 + m) * 1024 + n] =
                    (s * mv + addc - (n < m ? NEG : 0.0f)) * 0.125f;
            }
        }
    }
}

extern "C" void kernel_launch(void* const* d_in, const int* in_sizes, int n_in,
                              void* d_out, int out_size, void* d_ws, size_t ws_size,
                              hipStream_t stream) {
    const float* hs   = (const float*)d_in[0];   // [8,1024,768] f32
    const int*   mask = (const int*)d_in[1];     // [8,1024] i32
    const float* W    = (const float*)d_in[2];   // [768,1536] f32
    const float* bias = (const float*)d_in[3];   // [1536] f32
    float* out = (float*)d_out;                  // [8,12,1024,1024] f32

    char* ws = (char*)d_ws;
    unsigned short* qbuf = (unsigned short*)(ws + 0);           // 12,582,912 B
    unsigned short* kbuf = (unsigned short*)(ws + 12582912);    // 12,582,912 B
    unsigned short* hsb  = (unsigned short*)(ws + 25165824);    // 12,582,912 B
    unsigned short* wtb  = (unsigned short*)(ws + 37748736);    //  2,359,296 B
    float* cosT = (float*)(ws + 40108032);                      //    131,072 B
    float* sinT = (float*)(ws + 40239104);                      //    131,072 B

    cvt_bf16_kernel<<<6291456 / 4 / 256, 256, 0, stream>>>(hs, hsb, 6291456 / 4);
    transpose_w_kernel<<<dim3(48, 24), 256, 0, stream>>>(W, wtb);
    rope_table_kernel<<<128, 256, 0, stream>>>(cosT, sinT);
    proj_rope_kernel<<<dim3(12, 64), 256, 0, stream>>>(hsb, wtb, bias, cosT, sinT,
                                                       qbuf, kbuf);
    logits_kernel<<<dim3(8, 8, 96), 256, 0, stream>>>(qbuf, kbuf, mask, out);
}